// Round 1
// baseline (1612.755 us; speedup 1.0000x reference)
//
#include <hip/hip_runtime.h>
#include <hip/hip_bf16.h>

typedef _Float16 half8 __attribute__((ext_vector_type(8)));
typedef float floatx4 __attribute__((ext_vector_type(4)));

// ---------------------------------------------------------------------------
// async global->LDS, 16B per lane (wave-uniform LDS base + lane*16)
__device__ inline void gload_lds16(const void* g, void* l) {
  __builtin_amdgcn_global_load_lds(
      (const __attribute__((address_space(1))) unsigned int*)g,
      (__attribute__((address_space(3))) unsigned int*)l, 16, 0, 0);
}

// ---------------------------------------------------------------------------
// gates[n][e] = softmax_e( x[n] . gate_w[e] + gate_b[e] )   (one wave per row)
__global__ __launch_bounds__(256) void gates_kernel(
    const float* __restrict__ x, const float* __restrict__ gw,
    const float* __restrict__ gb, float* __restrict__ gates) {
  const int lane = threadIdx.x & 63, wid = threadIdx.x >> 6;
  const int n = blockIdx.x * 4 + wid;
  const float* xr = x + (size_t)n * 1024;
  float xv[16];
#pragma unroll
  for (int i = 0; i < 16; ++i) xv[i] = xr[lane + i * 64];
  float logit[8];
#pragma unroll
  for (int e = 0; e < 8; ++e) {
    const float* wr = gw + (size_t)e * 1024;
    float p = 0.f;
#pragma unroll
    for (int i = 0; i < 16; ++i) p += xv[i] * wr[lane + i * 64];
#pragma unroll
    for (int off = 32; off > 0; off >>= 1) p += __shfl_xor(p, off);
    logit[e] = p + gb[e];
  }
  float mx = logit[0];
#pragma unroll
  for (int e = 1; e < 8; ++e) mx = fmaxf(mx, logit[e]);
  float s = 0.f;
#pragma unroll
  for (int e = 0; e < 8; ++e) { logit[e] = expf(logit[e] - mx); s += logit[e]; }
  if (lane < 8) gates[(size_t)n * 8 + lane] = logit[lane] / s;
}

// ---------------------------------------------------------------------------
// fp32 -> fp16 bulk convert (8 elements/thread)
__global__ __launch_bounds__(256) void cvt_f32_f16_kernel(
    const float* __restrict__ in, _Float16* __restrict__ out, int n8) {
  const int i = blockIdx.x * 256 + threadIdx.x;
  if (i >= n8) return;
  const float4* p = (const float4*)(in + (size_t)i * 8);
  float4 a = p[0], b = p[1];
  half8 h;
  h[0] = (_Float16)a.x; h[1] = (_Float16)a.y; h[2] = (_Float16)a.z; h[3] = (_Float16)a.w;
  h[4] = (_Float16)b.x; h[5] = (_Float16)b.y; h[6] = (_Float16)b.z; h[7] = (_Float16)b.w;
  *(half8*)(out + (size_t)i * 8) = h;
}

// ---------------------------------------------------------------------------
// out[c][r] = (fp16) in[r][c]   — tiled transpose+convert, in: [R][C] fp32
__global__ __launch_bounds__(256) void transpose_cvt_kernel(
    const float* __restrict__ in, _Float16* __restrict__ out, int R, int C) {
  __shared__ _Float16 tile[32][33];
  const int tx = threadIdx.x & 31, ty = threadIdx.x >> 5;
  const int c0 = blockIdx.x << 5, r0 = blockIdx.y << 5;
#pragma unroll
  for (int i = 0; i < 4; ++i)
    tile[ty + i * 8][tx] = (_Float16)in[(size_t)(r0 + ty + i * 8) * C + c0 + tx];
  __syncthreads();
#pragma unroll
  for (int i = 0; i < 4; ++i)
    out[(size_t)(c0 + ty + i * 8) * R + r0 + tx] = tile[tx][ty + i * 8];
}

// ---------------------------------------------------------------------------
// 128x128-tile f16 MFMA GEMM, C = A[M][K] * Bt[Nn][K]^T
// EPI 0: Hout = relu(acc + bias)    (fp16 store)
// EPI 1: Out  (+)= gates[n][e] * (acc + bias)   (fp32, beta selects +=)
template <int EPI>
__global__ __launch_bounds__(256, 2) void gemm_kernel(
    const _Float16* __restrict__ A, const _Float16* __restrict__ Bt,
    const float* __restrict__ bias, const float* __restrict__ gates, int e,
    int beta, _Float16* __restrict__ Hout, float* __restrict__ Out, int M,
    int Nn, int K) {
  __shared__ _Float16 As[2][128 * 32];
  __shared__ _Float16 Bs[2][128 * 32];
  const int tid = threadIdx.x;
  const int lane = tid & 63;
  const int wid = tid >> 6;
  const int wr = wid >> 1, wc = wid & 1;  // 2x2 waves, 64x64 each
  const int m0 = blockIdx.x * 128, n0 = blockIdx.y * 128;

  floatx4 acc[4][4] = {};

  auto stage = [&](int buf, int kt) {
    const int k0 = kt << 5;
#pragma unroll
    for (int it = 0; it < 2; ++it) {
      const int s = tid + it * 256;  // 512 slots of 8 halves; A row-major [128][32]
      gload_lds16(A + (size_t)(m0 + (s >> 2)) * K + k0 + (s & 3) * 8,
                  &As[buf][s * 8]);
    }
#pragma unroll
    for (int it = 0; it < 2; ++it) {
      const int s = tid + it * 256;  // Bt tile [128 cols][32 k]
      gload_lds16(Bt + (size_t)(n0 + (s >> 2)) * K + k0 + (s & 3) * 8,
                  &Bs[buf][s * 8]);
    }
  };

  const int nk = K >> 5;
  stage(0, 0);
  __syncthreads();

  for (int kt = 0; kt < nk; ++kt) {
    const int cur = kt & 1;
    if (kt + 1 < nk) stage(cur ^ 1, kt + 1);
    const int krow = (lane >> 4) * 8;  // k-octet per lane-quad
    half8 af[4], bfr[4];
#pragma unroll
    for (int m = 0; m < 4; ++m) {
      const int row = wr * 64 + m * 16 + (lane & 15);
      af[m] = *(const half8*)&As[cur][row * 32 + krow];
    }
#pragma unroll
    for (int n = 0; n < 4; ++n) {
      const int row = wc * 64 + n * 16 + (lane & 15);
      bfr[n] = *(const half8*)&Bs[cur][row * 32 + krow];
    }
#pragma unroll
    for (int m = 0; m < 4; ++m)
#pragma unroll
      for (int n = 0; n < 4; ++n)
        acc[m][n] =
            __builtin_amdgcn_mfma_f32_16x16x32_f16(af[m], bfr[n], acc[m][n], 0, 0, 0);
    __syncthreads();  // drains vmcnt(0): next buffer staged, lds reads done
  }

  // epilogue: D-fragment col = lane&15, row = (lane>>4)*4 + r  [verified layout]
#pragma unroll
  for (int m = 0; m < 4; ++m) {
    const int gr0 = m0 + wr * 64 + m * 16 + ((lane >> 4) << 2);
#pragma unroll
    for (int n = 0; n < 4; ++n) {
      const int gc = n0 + wc * 64 + n * 16 + (lane & 15);
#pragma unroll
      for (int r = 0; r < 4; ++r) {
        const int gr = gr0 + r;
        const float v = acc[m][n][r] + bias[gc];
        if (EPI == 0) {
          Hout[(size_t)gr * Nn + gc] = (_Float16)fmaxf(v, 0.0f);
        } else {
          const float g = gates[(size_t)gr * 8 + e];
          float* p = Out + (size_t)gr * Nn + gc;
          float val = g * v;
          if (beta) val += *p;
          *p = val;
        }
      }
    }
  }
}

// ---------------------------------------------------------------------------
extern "C" void kernel_launch(void* const* d_in, const int* in_sizes, int n_in,
                              void* d_out, int out_size, void* d_ws,
                              size_t ws_size, hipStream_t stream) {
  const float* x  = (const float*)d_in[0];
  const float* gw = (const float*)d_in[1];
  const float* gb = (const float*)d_in[2];
  const float* w1 = (const float*)d_in[3];
  const float* b1 = (const float*)d_in[4];
  const float* w2 = (const float*)d_in[5];
  const float* b2 = (const float*)d_in[6];
  float* out = (float*)d_out;

  const int N = 8192, D = 1024, H = 4096, E = 8;

  char* ws = (char*)d_ws;
  float* gates   = (float*)ws;                                    // 256 KB
  _Float16* x_h  = (_Float16*)(ws + (1ull << 20));                // 16 MB
  _Float16* w1t  = (_Float16*)(ws + (1ull << 20) + (16ull << 20)); // 8 MB  [H][D]
  _Float16* w2t  = (_Float16*)(ws + (1ull << 20) + (24ull << 20)); // 8 MB  [D][H]
  _Float16* Hbuf = (_Float16*)(ws + (1ull << 20) + (32ull << 20)); // 64 MB [N][H]

  gates_kernel<<<N / 4, 256, 0, stream>>>(x, gw, gb, gates);
  cvt_f32_f16_kernel<<<(N * D / 8 + 255) / 256, 256, 0, stream>>>(x, x_h, N * D / 8);

  for (int e = 0; e < E; ++e) {
    // w1[e]: [D][H] -> w1t [H][D];  w2[e]: [H][D] -> w2t [D][H]
    transpose_cvt_kernel<<<dim3(H / 32, D / 32), 256, 0, stream>>>(
        w1 + (size_t)e * D * H, w1t, D, H);
    transpose_cvt_kernel<<<dim3(D / 32, H / 32), 256, 0, stream>>>(
        w2 + (size_t)e * H * D, w2t, H, D);
    gemm_kernel<0><<<dim3(N / 128, H / 128), 256, 0, stream>>>(
        x_h, w1t, b1 + (size_t)e * H, nullptr, 0, 0, Hbuf, nullptr, N, H, D);
    gemm_kernel<1><<<dim3(N / 128, D / 128), 256, 0, stream>>>(
        Hbuf, w2t, b2 + (size_t)e * D, gates, e, e > 0, nullptr, out, N, D, H);
  }
}